// Round 9
// baseline (122.277 us; speedup 1.0000x reference)
//
#include <hip/hip_runtime.h>
#include <hip/hip_bf16.h>
#include <math.h>

#define BTOT 32768

typedef _Float16 f16x8 __attribute__((ext_vector_type(8)));
typedef _Float16 f16x4 __attribute__((ext_vector_type(4)));
typedef float    f32x4 __attribute__((ext_vector_type(4)));

#define LDS_FENCE() asm volatile("s_waitcnt lgkmcnt(0)" ::: "memory")

__device__ __forceinline__ float ldin(const void* p, int i, int f32f) {
  return f32f ? ((const float*)p)[i]
              : __bfloat162float(((const __hip_bfloat16*)p)[i]);
}

__device__ __forceinline__ f32x4 MFMA(f16x8 a, f16x8 b, f32x4 c) {
  return __builtin_amdgcn_mfma_f32_16x16x32_f16(a, b, c, 0, 0, 0);
}

__device__ __forceinline__ float tanh_fast(float x) {
  float e = __expf(2.f * x);
  return 1.f - 2.f / (e + 1.f);
}

__device__ __forceinline__ float redq(float v) {
  v += __shfl_xor(v, 16, 64);
  v += __shfl_xor(v, 32, 64);
  return v;
}

// fragment-linear index: (h,k) -> LDS slot; A/B-frag reads lane-contiguous 16B.
__device__ __forceinline__ int widx(int h, int k) {
  return ((h >> 4) << 10) + ((k >> 5) << 9) + (((k >> 3) & 3) << 7) + ((h & 15) << 3) + (k & 7);
}

// ===========================================================================
// NN kernel (R8 structure minus QP tail): 256 blocks x 512 thr, 8 waves x 1
// 16-elem tile. Writes 6 scalars/elem to ws (R4-proven layout), V,H to out.
// ===========================================================================
__global__ __launch_bounds__(512, 2) void nn_kernel(
    const void* px, const void* pVW1, const void* pVb1, const void* pVW2, const void* pVb2,
    const void* pHW1, const void* pHb1, const void* pHW2, const void* pHb2,
    const void* pHW3, const void* pHb3, const void* pHW4, const void* pHb4,
    const void* pG0, const void* pK, float* WS, float* out)
{
  __shared__ __align__(16) _Float16 sVW2[4096], sVW2T[4096];
  __shared__ __align__(16) _Float16 sHW2[4096], sHW2T[4096];
  __shared__ __align__(16) _Float16 sHW3[4096], sHW3T[4096];
  __shared__ __align__(16) _Float16 sW1Vh[512], sW1Vl[512], sW1Hh[512], sW1Hl[512];
  __shared__ __align__(16) _Float16 sXh[1024], sXl[1024];
  __shared__ __align__(16) _Float16 sAVh[8][1024], sAVl[8][1024];
  __shared__ __align__(16) _Float16 sAHh[8][1024], sAHl[8][1024];
  __shared__ __align__(16) float sVb1[64], sVb2[64], sHb1[64], sHb2[64], sHb3[64], sW4[64];
  __shared__ __align__(16) float sWGV0[64], sWGV1[64], sWGH0[64], sWGH1[64];
  __shared__ float sHb4v;
  __shared__ int sCnt;

  const int tid = threadIdx.x, lane = tid & 63, wave = tid >> 6;
  const int m = lane & 15, q = lane >> 4;
  const int ro = q * 128 + m * 8;

  if (tid == 0) sCnt = 0;
  __syncthreads();
  {
    const unsigned short* xb = (const unsigned short*)px;
    int good = 0;
#pragma unroll
    for (int i = 0; i < 2; ++i) {
      int ex = (xb[tid * 2 + i] >> 7) & 0xFF;
      good += (ex >= 97 && ex <= 157) ? 1 : 0;
    }
    atomicAdd(&sCnt, good);
  }
  __syncthreads();
  const int f32f = (sCnt >= 870) ? 0 : 1;
  const bool wsplit = (f32f != 0);

  for (int i = tid; i < 4096; i += 512) {
    int h = i >> 6, k = i & 63;
    int fw = widx(h, k), tw = widx(k, h);
    sVW2[fw] = (_Float16)ldin(pVW2, i, f32f); sVW2T[tw] = sVW2[fw];
    sHW2[fw] = (_Float16)ldin(pHW2, i, f32f); sHW2T[tw] = sHW2[fw];
    sHW3[fw] = (_Float16)ldin(pHW3, i, f32f); sHW3T[tw] = sHW3[fw];
  }
  for (int i = tid; i < 512; i += 512) {
    float v = ldin(pVW1, i, f32f); _Float16 hh = (_Float16)v;
    sW1Vh[i] = hh; sW1Vl[i] = (_Float16)(v - (float)hh);
    v = ldin(pHW1, i, f32f); hh = (_Float16)v;
    sW1Hh[i] = hh; sW1Hl[i] = (_Float16)(v - (float)hh);
  }
  for (int i = tid; i < 1024; i += 512) {
    float v = ldin(px, blockIdx.x * 1024 + i, f32f); _Float16 hh = (_Float16)v;
    sXh[i] = hh; sXl[i] = (_Float16)(v - (float)hh);
  }
  if (tid < 64) {
    float a0 = 0.f, a1 = 0.f, b0 = 0.f, b1 = 0.f;
#pragma unroll
    for (int nn = 0; nn < 8; ++nn) {
      float g0 = ldin(pG0, 2 * nn, f32f), g1 = ldin(pG0, 2 * nn + 1, f32f);
      float wv = ldin(pVW1, tid * 8 + nn, f32f), wh = ldin(pHW1, tid * 8 + nn, f32f);
      a0 += wv * g0; a1 += wv * g1; b0 += wh * g0; b1 += wh * g1;
    }
    sWGV0[tid] = a0; sWGV1[tid] = a1; sWGH0[tid] = b0; sWGH1[tid] = b1;
    sVb1[tid] = ldin(pVb1, tid, f32f);
    sVb2[tid] = ldin(pVb2, tid, f32f);
    sHb1[tid] = ldin(pHb1, tid, f32f);
    sHb2[tid] = ldin(pHb2, tid, f32f);
    sHb3[tid] = ldin(pHb3, tid, f32f);
    sW4[tid]  = ldin(pHW4, tid, f32f);
  }
  if (tid == 0) sHb4v = ldin(pHb4, 0, f32f);
  __syncthreads();

  f16x8 zf;
#pragma unroll
  for (int i = 0; i < 8; ++i) zf[i] = (_Float16)0.f;

  _Float16 *aVh = sAVh[wave], *aVl = sAVl[wave];
  _Float16 *aHh = sAHh[wave], *aHl = sAHl[wave];
  const int tb = wave * 16;

  auto wgemm = [&](const _Float16* Wp, const _Float16* ah_, const _Float16* al_, f32x4* acc) {
    f16x8 b0h = *(const f16x8*)(ah_ + ro);
    f16x8 b1h = *(const f16x8*)(ah_ + 512 + ro);
    f16x8 b0l = *(const f16x8*)(al_ + ro);
    f16x8 b1l = *(const f16x8*)(al_ + 512 + ro);
#pragma unroll
    for (int ht = 0; ht < 4; ++ht) {
      const _Float16* ap = Wp + ht * 1024 + ro;
      f16x8 a0 = *(const f16x8*)ap, a1 = *(const f16x8*)(ap + 512);
      f32x4 c = {0.f, 0.f, 0.f, 0.f};
      c = MFMA(a0, b0h, c); c = MFMA(a1, b1h, c);
      c = MFMA(a0, b0l, c); c = MFMA(a1, b1l, c);
      acc[ht] = c;
    }
  };
  auto wstore = [&](const f32x4* vals, _Float16* ah_, _Float16* al_) {
#pragma unroll
    for (int ht = 0; ht < 4; ++ht) {
      int aw = ((ht >> 1) << 9) + (((ht & 1) * 2 + (q >> 1)) << 7) + m * 8 + ((q & 1) << 2);
      f16x4 vh, vl;
#pragma unroll
      for (int r = 0; r < 4; ++r) {
        float x = vals[ht][r];
        _Float16 hh = (_Float16)x;
        vh[r] = hh; vl[r] = (_Float16)(x - (float)hh);
      }
      *(f16x4*)(ah_ + aw) = vh;
      *(f16x4*)(al_ + aw) = vl;
    }
  };
  auto l1gemm = [&](const _Float16* W1h, const _Float16* W1l, f32x4* acc) {
    f16x8 xbh = zf, xbl = zf;
    if (lane < 16) {
      xbh = *(const f16x8*)(sXh + (tb + m) * 8);
      xbl = *(const f16x8*)(sXl + (tb + m) * 8);
    }
#pragma unroll
    for (int ht = 0; ht < 4; ++ht) {
      f16x8 afh = zf, afl = zf;
      if (lane < 16) {
        afh = *(const f16x8*)(W1h + (ht * 16 + m) * 8);
        afl = *(const f16x8*)(W1l + (ht * 16 + m) * 8);
      }
      f32x4 c = {0.f, 0.f, 0.f, 0.f};
      c = MFMA(afh, xbh, c);
      c = MFMA(afh, xbl, c);
      if (wsplit) c = MFMA(afl, xbh, c);
      acc[ht] = c;
    }
  };

  f32x4 accV[4], accH[4], z1V[4], z1H[4], d1V[4], d1H[4], d2H[4], tvV[4], tvH[4];

  // stage A
  l1gemm(sW1Vh, sW1Vl, accV);
  l1gemm(sW1Hh, sW1Hl, accH);
#pragma unroll
  for (int ht = 0; ht < 4; ++ht) {
    z1V[ht] = accV[ht]; z1H[ht] = accH[ht];
    f32x4 bV = *(const f32x4*)&sVb1[ht * 16 + q * 4];
    f32x4 bH = *(const f32x4*)&sHb1[ht * 16 + q * 4];
#pragma unroll
    for (int r = 0; r < 4; ++r) {
      float t = tanh_fast(z1V[ht][r] + bV[r]);
      tvV[ht][r] = t; d1V[ht][r] = 1.f - t * t;
      t = tanh_fast(z1H[ht][r] + bH[r]);
      tvH[ht][r] = t; d1H[ht][r] = 1.f - t * t;
    }
  }
  wstore(tvV, aVh, aVl);
  wstore(tvH, aHh, aHl);
  LDS_FENCE();

  // stage B
  wgemm(sVW2, aVh, aVl, accV);
  wgemm(sHW2, aHh, aHl, accH);
  float pV = 0.f;
#pragma unroll
  for (int ht = 0; ht < 4; ++ht) {
    f32x4 bV = *(const f32x4*)&sVb2[ht * 16 + q * 4];
    f32x4 bH = *(const f32x4*)&sHb2[ht * 16 + q * 4];
#pragma unroll
    for (int r = 0; r < 4; ++r) {
      float t = tanh_fast(accV[ht][r] + bV[r]);
      pV += t * t;
      tvV[ht][r] = t * (1.f - t * t);
      t = tanh_fast(accH[ht][r] + bH[r]);
      tvH[ht][r] = t; d2H[ht][r] = 1.f - t * t;
    }
  }
  wstore(tvV, aVh, aVl);
  wstore(tvH, aHh, aHl);
  LDS_FENCE();

  // stage C
  wgemm(sVW2T, aVh, aVl, accV);
  wgemm(sHW3, aHh, aHl, accH);
  float pgvx = 0.f, plv0 = 0.f, plv1 = 0.f, pH = 0.f;
#pragma unroll
  for (int ht = 0; ht < 4; ++ht) {
    f32x4 g0 = *(const f32x4*)&sWGV0[ht * 16 + q * 4];
    f32x4 g1 = *(const f32x4*)&sWGV1[ht * 16 + q * 4];
    f32x4 bH = *(const f32x4*)&sHb3[ht * 16 + q * 4];
    f32x4 w4 = *(const f32x4*)&sW4[ht * 16 + q * 4];
#pragma unroll
    for (int r = 0; r < 4; ++r) {
      float wt = accV[ht][r] * d1V[ht][r];
      pgvx += wt * z1V[ht][r];
      plv0 += wt * g0[r]; plv1 += wt * g1[r];
      float t = tanh_fast(accH[ht][r] + bH[r]);
      pH += t * w4[r];
      tvH[ht][r] = w4[r] * (1.f - t * t);
    }
  }
  wstore(tvH, aHh, aHl);
  LDS_FENCE();

  // stage D
  wgemm(sHW3T, aHh, aHl, accH);
#pragma unroll
  for (int ht = 0; ht < 4; ++ht)
#pragma unroll
    for (int r = 0; r < 4; ++r) tvH[ht][r] = accH[ht][r] * d2H[ht][r];
  wstore(tvH, aHh, aHl);
  LDS_FENCE();

  // stage E
  wgemm(sHW2T, aHh, aHl, accH);
  float pghx = 0.f, plh0 = 0.f, plh1 = 0.f;
#pragma unroll
  for (int ht = 0; ht < 4; ++ht) {
    f32x4 g0 = *(const f32x4*)&sWGH0[ht * 16 + q * 4];
    f32x4 g1 = *(const f32x4*)&sWGH1[ht * 16 + q * 4];
#pragma unroll
    for (int r = 0; r < 4; ++r) {
      float wt = accH[ht][r] * d1H[ht][r];
      pghx += wt * z1H[ht][r];
      plh0 += wt * g0[r]; plh1 += wt * g1[r];
    }
  }

  {
    float rgvx = redq(pgvx), rlv0 = redq(plv0), rlv1 = redq(plv1), rV = 0.5f * redq(pV);
    float rghx = redq(pghx), rlh0 = redq(plh0), rlh1 = redq(plh1), rH = redq(pH) + sHb4v;
    if (lane < 16) {
      int e = blockIdx.x * 128 + tb + lane;
      WS[0 * BTOT + e] = rlh0;  WS[1 * BTOT + e] = rlh1;
      WS[2 * BTOT + e] = rlv0;  WS[3 * BTOT + e] = rlv1;
      WS[4 * BTOT + e] = rghx;  WS[5 * BTOT + e] = rgvx;
      out[98304 + e]  = rV;
      out[163840 + e] = rH;
    }
  }
}

// ===========================================================================
// QP kernel: 512 blocks x 64 thr, one 80-iter ADMM per thread.
// Schur-complement x-update: 6x6 solve -> precomputed 2x2 inverse + cheap
// back-substitution (exact same linear system as Gauss-Jordan version).
// ===========================================================================
__global__ __launch_bounds__(64) void qp_kernel(const void* px, const void* pK,
                                                const float* WS, float* out) {
  __shared__ int sCnt;
  const int tid = threadIdx.x;
  if (tid == 0) sCnt = 0;
  __syncthreads();
  {
    const unsigned short* xb = (const unsigned short*)px;
    int good = 0;
#pragma unroll
    for (int i = 0; i < 2; ++i) {
      int ex = (xb[tid * 2 + i] >> 7) & 0xFF;
      good += (ex >= 97 && ex <= 157) ? 1 : 0;
    }
    atomicAdd(&sCnt, good);
  }
  __syncthreads();
  const int f32f = (sCnt >= 109) ? 0 : 1;   // 85% of 128 samples

  const int e = blockIdx.x * 64 + tid;
  const float im = 1.0f / 1.2f;
  const float sg = 1e-6f;

  float gh0 = WS[0 * BTOT + e], gh1 = WS[1 * BTOT + e];
  float gv0 = WS[2 * BTOT + e], gv1 = WS[3 * BTOT + e];
  float ghx = WS[4 * BTOT + e], gvx = WS[5 * BTOT + e];
  float V = out[98304 + e], H = out[163840 + e];

  float un0 = 0.f, un1 = 0.f;
#pragma unroll
  for (int n = 0; n < 8; ++n) {
    float xv = ldin(px, e * 8 + n, f32f);
    un0 -= xv * ldin(pK, 2 * n, f32f);
    un1 -= xv * ldin(pK, 2 * n + 1, f32f);
  }

  float lo0 = ghx - H;
  float hi1 = gvx - V;
  float lo2 = ghx * im - H;
  float hi3 = gvx * im - V;
  float qv0 = -2.f * un0, qv1 = -2.f * un1;

  // Schur setup: M = [[B2,C],[C^T,dI]], d=2+sg, CC^T = al*(gh gh^T + gv gv^T)
  const float d  = 2.f + sg;
  const float rd = 1.f / d;
  const float al = 1.f + im * im;
  const float be = al * (1.f - rd);
  float S00 = be * (gh0 * gh0 + gv0 * gv0) + d;
  float S11 = be * (gh1 * gh1 + gv1 * gv1) + d;
  float S01 = be * (gh0 * gh1 + gv0 * gv1);
  float idet = 1.f / (S00 * S11 - S01 * S01);
  float i00 = S11 * idet, i11 = S00 * idet, i01 = -S01 * idet;

  float X0 = 0.f, X1 = 0.f, X2 = 0.f, X3 = 0.f, X4 = 0.f, X5 = 0.f;
  float Z[8] = {0.f, 0.f, 0.f, 0.f, 0.f, 0.f, 0.f, 0.f};
  float Y[8] = {0.f, 0.f, 0.f, 0.f, 0.f, 0.f, 0.f, 0.f};

#pragma unroll 1
  for (int it = 0; it < 80; ++it) {
    float t0 = Z[0] - Y[0], t1 = Z[1] - Y[1], t2 = Z[2] - Y[2], t3 = Z[3] - Y[3];
    float t4 = Z[4] - Y[4], t5 = Z[5] - Y[5], t6 = Z[6] - Y[6], t7 = Z[7] - Y[7];
    float tauh = t0 + im * t2, tauv = t1 + im * t3;
    float b0 = sg * X0 - qv0 + gh0 * tauh + gv0 * tauv;
    float b1 = sg * X1 - qv1 + gh1 * tauh + gv1 * tauv;
    float b2 = sg * X2 - 100.f - t1 + t4;
    float b3 = sg * X3 - 100.f - t3 + t5;
    float b4 = sg * X4 - 50.f + t0 + t6;
    float b5 = sg * X5 - 50.f + t2 + t7;
    // u-solve via Schur: u = Sinv (b1 - C b2 / d)
    float p  = b2 + im * b3;
    float s2 = b4 + im * b5;
    float cb0 = gh0 * s2 - gv0 * p;
    float cb1 = gh1 * s2 - gv1 * p;
    float u0b = b0 - cb0 * rd;
    float u1b = b1 - cb1 * rd;
    X0 = i00 * u0b + i01 * u1b;
    X1 = i01 * u0b + i11 * u1b;
    float gdH = gh0 * X0 + gh1 * X1;
    float gdV = gv0 * X0 + gv1 * X1;
    X2 = (b2 + gdV) * rd;
    X3 = (b3 + im * gdV) * rd;
    X4 = (b4 - gdH) * rd;
    X5 = (b5 - im * gdH) * rd;
    float zt0 = gdH + X4;
    float zt1 = gdV - X2;
    float zt2 = gdH * im + X5;
    float zt3 = gdV * im - X3;

    float v, zn;
    v = zt0 + Y[0]; zn = fmaxf(v, lo0); Y[0] += zt0 - zn; Z[0] = zn;
    v = zt1 + Y[1]; zn = fminf(v, hi1); Y[1] += zt1 - zn; Z[1] = zn;
    v = zt2 + Y[2]; zn = fmaxf(v, lo2); Y[2] += zt2 - zn; Z[2] = zn;
    v = zt3 + Y[3]; zn = fminf(v, hi3); Y[3] += zt3 - zn; Z[3] = zn;
    v = X2 + Y[4];  zn = fmaxf(v, 0.f); Y[4] += X2 - zn;  Z[4] = zn;
    v = X3 + Y[5];  zn = fmaxf(v, 0.f); Y[5] += X3 - zn;  Z[5] = zn;
    v = X4 + Y[6];  zn = fmaxf(v, 0.f); Y[6] += X4 - zn;  Z[6] = zn;
    v = X5 + Y[7];  zn = fmaxf(v, 0.f); Y[7] += X5 - zn;  Z[7] = zn;
  }

  float relax = 0.5f * (X2 + X3);
  const float cc = 0.5f * (1.f + im);
  float Vdot = cc * (gv0 * X0 + gv1 * X1 - gvx);
  float Hdot = cc * (gh0 * X0 + gh1 * X1 - ghx);

  out[2 * e]      = X0;
  out[2 * e + 1]  = X1;
  out[65536 + e]  = relax;
  out[131072 + e] = Vdot;
  out[196608 + e] = Hdot;
}

extern "C" void kernel_launch(void* const* d_in, const int* in_sizes, int n_in,
                              void* d_out, int out_size, void* d_ws, size_t ws_size,
                              hipStream_t stream) {
  float* out = (float*)d_out;
  float* WS  = (float*)d_ws;   // 6 x 32768 f32 = 768 KB (R4-proven layout)
  nn_kernel<<<256, 512, 0, stream>>>(
      d_in[0], d_in[1], d_in[2], d_in[3], d_in[4],
      d_in[5], d_in[6], d_in[7], d_in[8],
      d_in[9], d_in[10], d_in[11], d_in[12],
      d_in[13], d_in[14], WS, out);
  qp_kernel<<<512, 64, 0, stream>>>(d_in[0], d_in[14], WS, out);
}

// Round 10
// 121.637 us; speedup vs baseline: 1.0053x; 1.0053x over previous
//
#include <hip/hip_runtime.h>
#include <hip/hip_bf16.h>
#include <math.h>

#define BTOT 32768

typedef _Float16 f16x8 __attribute__((ext_vector_type(8)));
typedef _Float16 f16x4 __attribute__((ext_vector_type(4)));
typedef float    f32x4 __attribute__((ext_vector_type(4)));

#define LDS_FENCE() asm volatile("s_waitcnt lgkmcnt(0)" ::: "memory")

__device__ __forceinline__ float ldin(const void* p, int i, int f32f) {
  return f32f ? ((const float*)p)[i]
              : __bfloat162float(((const __hip_bfloat16*)p)[i]);
}

__device__ __forceinline__ f32x4 MFMA(f16x8 a, f16x8 b, f32x4 c) {
  return __builtin_amdgcn_mfma_f32_16x16x32_f16(a, b, c, 0, 0, 0);
}

// tanh via fast exp + hw rcp (v_rcp_f32 ~1ulp, far below fp16 staging noise)
__device__ __forceinline__ float tanh_fast(float x) {
  float e = __expf(2.f * x);
  return 1.f - 2.f * __builtin_amdgcn_rcpf(e + 1.f);
}

__device__ __forceinline__ float redq(float v) {
  v += __shfl_xor(v, 16, 64);
  v += __shfl_xor(v, 32, 64);
  return v;
}

// fragment-linear index: (h,k) -> LDS slot; A/B-frag reads lane-contiguous 16B.
__device__ __forceinline__ int widx(int h, int k) {
  return ((h >> 4) << 10) + ((k >> 5) << 9) + (((k >> 3) & 3) << 7) + ((h & 15) << 3) + (k & 7);
}

// out layout (f32): u[2B] | relax[B] | V[B] | Vdot[B] | H[B] | Hdot[B]
__global__ __launch_bounds__(512, 4) void fused_kernel(
    const void* px, const void* pVW1, const void* pVb1, const void* pVW2, const void* pVb2,
    const void* pHW1, const void* pHb1, const void* pHW2, const void* pHb2,
    const void* pHW3, const void* pHb3, const void* pHW4, const void* pHb4,
    const void* pG0, const void* pK, float* out)
{
  __shared__ __align__(16) _Float16 sVW2[4096], sVW2T[4096];
  __shared__ __align__(16) _Float16 sHW2[4096], sHW2T[4096];
  __shared__ __align__(16) _Float16 sHW3[4096], sHW3T[4096];
  __shared__ __align__(16) _Float16 sW1Vh[512], sW1Vl[512], sW1Hh[512], sW1Hl[512];
  __shared__ __align__(16) _Float16 sAct[8][1024];   // shared V/H act (hi-only), per wave
  __shared__ __align__(16) float sVb1[64], sVb2[64], sHb1[64], sHb2[64], sHb3[64], sW4[64];
  __shared__ __align__(16) float sWGV0[64], sWGV1[64], sWGH0[64], sWGH1[64];
  __shared__ __align__(16) float sQP[128][11];       // stride 11: conflict-free column reads
  __shared__ float sKv[16], sHb4v;
  __shared__ int sCnt;

  const int tid = threadIdx.x, lane = tid & 63, wave = tid >> 6;
  const int m = lane & 15, q = lane >> 4;
  const int ro = q * 128 + m * 8;

  // ---- input-dtype detection (bf16-halves exponent-window vote) ----
  if (tid == 0) sCnt = 0;
  __syncthreads();
  {
    const unsigned short* xb = (const unsigned short*)px;
    int good = 0;
#pragma unroll
    for (int i = 0; i < 2; ++i) {
      int ex = (xb[tid * 2 + i] >> 7) & 0xFF;
      good += (ex >= 97 && ex <= 157) ? 1 : 0;
    }
    atomicAdd(&sCnt, good);
  }
  __syncthreads();
  const int f32f = (sCnt >= 870) ? 0 : 1;
  const bool wsplit = (f32f != 0);

  // ---- stage weights into fragment-linear fp16 panels (+transposes), consts ----
  for (int i = tid; i < 4096; i += 512) {
    int h = i >> 6, k = i & 63;
    int fw = widx(h, k), tw = widx(k, h);
    sVW2[fw] = (_Float16)ldin(pVW2, i, f32f); sVW2T[tw] = sVW2[fw];
    sHW2[fw] = (_Float16)ldin(pHW2, i, f32f); sHW2T[tw] = sHW2[fw];
    sHW3[fw] = (_Float16)ldin(pHW3, i, f32f); sHW3T[tw] = sHW3[fw];
  }
  for (int i = tid; i < 512; i += 512) {
    float v = ldin(pVW1, i, f32f); _Float16 hh = (_Float16)v;
    sW1Vh[i] = hh; sW1Vl[i] = (_Float16)(v - (float)hh);
    v = ldin(pHW1, i, f32f); hh = (_Float16)v;
    sW1Hh[i] = hh; sW1Hl[i] = (_Float16)(v - (float)hh);
  }
  if (tid < 64) {
    float a0 = 0.f, a1 = 0.f, b0 = 0.f, b1 = 0.f;
#pragma unroll
    for (int nn = 0; nn < 8; ++nn) {
      float g0 = ldin(pG0, 2 * nn, f32f), g1 = ldin(pG0, 2 * nn + 1, f32f);
      float wv = ldin(pVW1, tid * 8 + nn, f32f), wh = ldin(pHW1, tid * 8 + nn, f32f);
      a0 += wv * g0; a1 += wv * g1; b0 += wh * g0; b1 += wh * g1;
    }
    sWGV0[tid] = a0; sWGV1[tid] = a1; sWGH0[tid] = b0; sWGH1[tid] = b1;
    sVb1[tid] = ldin(pVb1, tid, f32f);
    sVb2[tid] = ldin(pVb2, tid, f32f);
    sHb1[tid] = ldin(pHb1, tid, f32f);
    sHb2[tid] = ldin(pHb2, tid, f32f);
    sHb3[tid] = ldin(pHb3, tid, f32f);
    sW4[tid]  = ldin(pHW4, tid, f32f);
  }
  if (tid < 16) sKv[tid] = ldin(pK, tid, f32f);
  if (tid == 0) sHb4v = ldin(pHb4, 0, f32f);
  __syncthreads();

  f16x8 zf;
#pragma unroll
  for (int i = 0; i < 8; ++i) zf[i] = (_Float16)0.f;

  _Float16* act = sAct[wave];
  const int tb = wave * 16;
  const int e0 = blockIdx.x * 128 + tb;

  // x B-frag (hi/lo) straight from global into registers — no LDS
  f16x8 xbh = zf, xbl = zf;
  if (lane < 16) {
#pragma unroll
    for (int n = 0; n < 8; ++n) {
      float v = ldin(px, (e0 + m) * 8 + n, f32f);
      _Float16 hh = (_Float16)v;
      xbh[n] = hh; xbl[n] = (_Float16)(v - (float)hh);
    }
  }

  // 64x64 GEMM from fragment-linear panel + hi-only activations (8 MFMA)
  auto wgemm = [&](const _Float16* Wp, f32x4* acc) {
    f16x8 b0 = *(const f16x8*)(act + ro);
    f16x8 b1 = *(const f16x8*)(act + 512 + ro);
#pragma unroll
    for (int ht = 0; ht < 4; ++ht) {
      const _Float16* ap = Wp + ht * 1024 + ro;
      f32x4 c = {0.f, 0.f, 0.f, 0.f};
      c = MFMA(*(const f16x8*)ap, b0, c);
      c = MFMA(*(const f16x8*)(ap + 512), b1, c);
      acc[ht] = c;
    }
  };
  auto wstore = [&](const f32x4* vals) {
#pragma unroll
    for (int ht = 0; ht < 4; ++ht) {
      int aw = ((ht >> 1) << 9) + (((ht & 1) * 2 + (q >> 1)) << 7) + m * 8 + ((q & 1) << 2);
      f16x4 vh;
#pragma unroll
      for (int r = 0; r < 4; ++r) vh[r] = (_Float16)vals[ht][r];
      *(f16x4*)(act + aw) = vh;
    }
  };
  auto l1gemm = [&](const _Float16* W1h, const _Float16* W1l, f32x4* acc) {
#pragma unroll
    for (int ht = 0; ht < 4; ++ht) {
      f16x8 afh = zf, afl = zf;
      if (lane < 16) {
        afh = *(const f16x8*)(W1h + (ht * 16 + m) * 8);
        afl = *(const f16x8*)(W1l + (ht * 16 + m) * 8);
      }
      f32x4 c = {0.f, 0.f, 0.f, 0.f};
      c = MFMA(afh, xbh, c);
      c = MFMA(afh, xbl, c);
      if (wsplit) c = MFMA(afl, xbh, c);
      acc[ht] = c;
    }
  };

  f32x4 acc[4], z1[4], d1[4], d2[4], tv[4];

  // ================= V net (sequential, shared act buffer) =================
  l1gemm(sW1Vh, sW1Vl, acc);
#pragma unroll
  for (int ht = 0; ht < 4; ++ht) {
    z1[ht] = acc[ht];
    f32x4 b4 = *(const f32x4*)&sVb1[ht * 16 + q * 4];
#pragma unroll
    for (int r = 0; r < 4; ++r) {
      float t = tanh_fast(z1[ht][r] + b4[r]);
      tv[ht][r] = t; d1[ht][r] = 1.f - t * t;
    }
  }
  wstore(tv); LDS_FENCE();

  wgemm(sVW2, acc);
  float pV = 0.f;
#pragma unroll
  for (int ht = 0; ht < 4; ++ht) {
    f32x4 b4 = *(const f32x4*)&sVb2[ht * 16 + q * 4];
#pragma unroll
    for (int r = 0; r < 4; ++r) {
      float t = tanh_fast(acc[ht][r] + b4[r]);
      pV += t * t;
      tv[ht][r] = t * (1.f - t * t);     // a = t2*d2
    }
  }
  wstore(tv); LDS_FENCE();

  wgemm(sVW2T, acc);                     // wk
  float pgvx = 0.f, plv0 = 0.f, plv1 = 0.f;
#pragma unroll
  for (int ht = 0; ht < 4; ++ht) {
    f32x4 g0 = *(const f32x4*)&sWGV0[ht * 16 + q * 4];
    f32x4 g1 = *(const f32x4*)&sWGV1[ht * 16 + q * 4];
#pragma unroll
    for (int r = 0; r < 4; ++r) {
      float wt = acc[ht][r] * d1[ht][r];
      pgvx += wt * z1[ht][r];
      plv0 += wt * g0[r]; plv1 += wt * g1[r];
    }
  }

  // ================= H net =================
  l1gemm(sW1Hh, sW1Hl, acc);
#pragma unroll
  for (int ht = 0; ht < 4; ++ht) {
    z1[ht] = acc[ht];
    f32x4 b4 = *(const f32x4*)&sHb1[ht * 16 + q * 4];
#pragma unroll
    for (int r = 0; r < 4; ++r) {
      float t = tanh_fast(z1[ht][r] + b4[r]);
      tv[ht][r] = t; d1[ht][r] = 1.f - t * t;
    }
  }
  wstore(tv); LDS_FENCE();

  wgemm(sHW2, acc);
#pragma unroll
  for (int ht = 0; ht < 4; ++ht) {
    f32x4 b4 = *(const f32x4*)&sHb2[ht * 16 + q * 4];
#pragma unroll
    for (int r = 0; r < 4; ++r) {
      float t = tanh_fast(acc[ht][r] + b4[r]);
      tv[ht][r] = t; d2[ht][r] = 1.f - t * t;
    }
  }
  wstore(tv); LDS_FENCE();

  wgemm(sHW3, acc);
  float pH = 0.f;
#pragma unroll
  for (int ht = 0; ht < 4; ++ht) {
    f32x4 b4 = *(const f32x4*)&sHb3[ht * 16 + q * 4];
    f32x4 w4 = *(const f32x4*)&sW4[ht * 16 + q * 4];
#pragma unroll
    for (int r = 0; r < 4; ++r) {
      float t = tanh_fast(acc[ht][r] + b4[r]);
      pH += t * w4[r];
      tv[ht][r] = w4[r] * (1.f - t * t);   // v4
    }
  }
  wstore(tv); LDS_FENCE();

  wgemm(sHW3T, acc);                       // v3
#pragma unroll
  for (int ht = 0; ht < 4; ++ht)
#pragma unroll
    for (int r = 0; r < 4; ++r) tv[ht][r] = acc[ht][r] * d2[ht][r];  // bb
  wstore(tv); LDS_FENCE();

  wgemm(sHW2T, acc);                       // v2
  float pghx = 0.f, plh0 = 0.f, plh1 = 0.f;
#pragma unroll
  for (int ht = 0; ht < 4; ++ht) {
    f32x4 g0 = *(const f32x4*)&sWGH0[ht * 16 + q * 4];
    f32x4 g1 = *(const f32x4*)&sWGH1[ht * 16 + q * 4];
#pragma unroll
    for (int r = 0; r < 4; ++r) {
      float wt = acc[ht][r] * d1[ht][r];
      pghx += wt * z1[ht][r];
      plh0 += wt * g0[r]; plh1 += wt * g1[r];
    }
  }

  // ---- reduce over quads, stash per-element scalars ----
  {
    float rgvx = redq(pgvx), rlv0 = redq(plv0), rlv1 = redq(plv1), rV = 0.5f * redq(pV);
    float rghx = redq(pghx), rlh0 = redq(plh0), rlh1 = redq(plh1), rH = redq(pH) + sHb4v;
    if (lane < 16) {
      int el = tb + lane;
      sQP[el][0] = rlh0;  sQP[el][1] = rlh1;
      sQP[el][2] = rlv0;  sQP[el][3] = rlv1;
      sQP[el][4] = rghx;  sQP[el][5] = rgvx;
      sQP[el][6] = rV;    sQP[el][7] = rH;
      out[98304 + e0 + lane]  = rV;
      out[163840 + e0 + lane] = rH;
    }
  }
  __syncthreads();

  // ====== QP phase: 128 threads, Schur-complement ADMM (verified R9) ======
  if (tid >= 128) return;
  const int e = blockIdx.x * 128 + tid;
  const float im = 1.0f / 1.2f;
  const float sg = 1e-6f;

  float gh0 = sQP[tid][0], gh1 = sQP[tid][1];
  float gv0 = sQP[tid][2], gv1 = sQP[tid][3];
  float ghx = sQP[tid][4], gvx = sQP[tid][5];
  float V   = sQP[tid][6], H   = sQP[tid][7];

  float un0 = 0.f, un1 = 0.f;
#pragma unroll
  for (int n = 0; n < 8; ++n) {
    float xv = ldin(px, e * 8 + n, f32f);
    un0 -= xv * sKv[2 * n];
    un1 -= xv * sKv[2 * n + 1];
  }

  float lo0 = ghx - H;
  float hi1 = gvx - V;
  float lo2 = ghx * im - H;
  float hi3 = gvx * im - V;
  float qv0 = -2.f * un0, qv1 = -2.f * un1;

  const float d  = 2.f + sg;
  const float rd = 1.f / d;
  const float al = 1.f + im * im;
  const float be = al * (1.f - rd);
  float S00 = be * (gh0 * gh0 + gv0 * gv0) + d;
  float S11 = be * (gh1 * gh1 + gv1 * gv1) + d;
  float S01 = be * (gh0 * gh1 + gv0 * gv1);
  float idet = 1.f / (S00 * S11 - S01 * S01);
  float i00 = S11 * idet, i11 = S00 * idet, i01 = -S01 * idet;

  float X0 = 0.f, X1 = 0.f, X2 = 0.f, X3 = 0.f, X4 = 0.f, X5 = 0.f;
  float Z[8] = {0.f, 0.f, 0.f, 0.f, 0.f, 0.f, 0.f, 0.f};
  float Y[8] = {0.f, 0.f, 0.f, 0.f, 0.f, 0.f, 0.f, 0.f};

#pragma unroll 1
  for (int it = 0; it < 80; ++it) {
    float t0 = Z[0] - Y[0], t1 = Z[1] - Y[1], t2 = Z[2] - Y[2], t3 = Z[3] - Y[3];
    float t4 = Z[4] - Y[4], t5 = Z[5] - Y[5], t6 = Z[6] - Y[6], t7 = Z[7] - Y[7];
    float tauh = t0 + im * t2, tauv = t1 + im * t3;
    float b0 = sg * X0 - qv0 + gh0 * tauh + gv0 * tauv;
    float b1 = sg * X1 - qv1 + gh1 * tauh + gv1 * tauv;
    float b2 = sg * X2 - 100.f - t1 + t4;
    float b3 = sg * X3 - 100.f - t3 + t5;
    float b4 = sg * X4 - 50.f + t0 + t6;
    float b5 = sg * X5 - 50.f + t2 + t7;
    float p  = b2 + im * b3;
    float s2 = b4 + im * b5;
    float cb0 = gh0 * s2 - gv0 * p;
    float cb1 = gh1 * s2 - gv1 * p;
    float u0b = b0 - cb0 * rd;
    float u1b = b1 - cb1 * rd;
    X0 = i00 * u0b + i01 * u1b;
    X1 = i01 * u0b + i11 * u1b;
    float gdH = gh0 * X0 + gh1 * X1;
    float gdV = gv0 * X0 + gv1 * X1;
    X2 = (b2 + gdV) * rd;
    X3 = (b3 + im * gdV) * rd;
    X4 = (b4 - gdH) * rd;
    X5 = (b5 - im * gdH) * rd;
    float zt0 = gdH + X4;
    float zt1 = gdV - X2;
    float zt2 = gdH * im + X5;
    float zt3 = gdV * im - X3;

    float v, zn;
    v = zt0 + Y[0]; zn = fmaxf(v, lo0); Y[0] += zt0 - zn; Z[0] = zn;
    v = zt1 + Y[1]; zn = fminf(v, hi1); Y[1] += zt1 - zn; Z[1] = zn;
    v = zt2 + Y[2]; zn = fmaxf(v, lo2); Y[2] += zt2 - zn; Z[2] = zn;
    v = zt3 + Y[3]; zn = fminf(v, hi3); Y[3] += zt3 - zn; Z[3] = zn;
    v = X2 + Y[4];  zn = fmaxf(v, 0.f); Y[4] += X2 - zn;  Z[4] = zn;
    v = X3 + Y[5];  zn = fmaxf(v, 0.f); Y[5] += X3 - zn;  Z[5] = zn;
    v = X4 + Y[6];  zn = fmaxf(v, 0.f); Y[6] += X4 - zn;  Z[6] = zn;
    v = X5 + Y[7];  zn = fmaxf(v, 0.f); Y[7] += X5 - zn;  Z[7] = zn;
  }

  float relax = 0.5f * (X2 + X3);
  const float cc = 0.5f * (1.f + im);
  float Vdot = cc * (gv0 * X0 + gv1 * X1 - gvx);
  float Hdot = cc * (gh0 * X0 + gh1 * X1 - ghx);

  out[2 * e]      = X0;
  out[2 * e + 1]  = X1;
  out[65536 + e]  = relax;
  out[131072 + e] = Vdot;
  out[196608 + e] = Hdot;
}

extern "C" void kernel_launch(void* const* d_in, const int* in_sizes, int n_in,
                              void* d_out, int out_size, void* d_ws, size_t ws_size,
                              hipStream_t stream) {
  float* out = (float*)d_out;
  fused_kernel<<<256, 512, 0, stream>>>(
      d_in[0], d_in[1], d_in[2], d_in[3], d_in[4],
      d_in[5], d_in[6], d_in[7], d_in[8],
      d_in[9], d_in[10], d_in[11], d_in[12],
      d_in[13], d_in[14], out);
}